// Round 11
// baseline (14644.405 us; speedup 1.0000x reference)
//
#include <hip/hip_runtime.h>
#include <stdint.h>

#define V 4096
#define D 128
#define E 12288
#define NPAD 16384
#define HALF 8192
#define TARGET 2048
#define MAXM (V - TARGET)     // 2048 merges max
#define ECAP 192              // per-cluster incident-edge list capacity (u32 entries)
#define HSLOTS 32768          // pair-count hash slots (128 KB LDS)

// ws layout (bytes)
#define WS_BM     0u                                  // V*V/8 = 2 MB canonical dedupe bitmap
#define WS_ELIST  (V * (V / 8u))                      // V*ECAP*4 = 3 MB
#define WS_ELEN   (WS_ELIST + V * ECAP * 4u)          // V u32
#define WS_DEDUP  (WS_ELEN + V * 4u)                  // E u8
#define WS_PRI    (WS_DEDUP + E)                      // V f32
#define WS_KEYS   (WS_PRI + V * 4u)                   // NPAD u64
#define WS_PK     (WS_KEYS + NPAD * 8u)               // E u32 (sorted packed edges)
#define WS_PAIRS  (WS_PK + E * 4u)                    // MAXM u32
#define WS_MCOUNT (WS_PAIRS + MAXM * 4u)              // int

// build: canonical-pair dedupe bitmap + per-vertex incident edge lists (canonical pair key)
__global__ void k_build(const int* __restrict__ edges, unsigned* __restrict__ bm,
                        unsigned* __restrict__ elenG, unsigned* __restrict__ elist,
                        uint8_t* __restrict__ dedup) {
    int e = blockIdx.x * 256 + threadIdx.x;
    if (e < E) {
        int a = edges[e], b = edges[E + e];
        int mn = a < b ? a : b, mx = a < b ? b : a;
        unsigned old = atomicOr(&bm[mn * (V / 32) + (mx >> 5)], 1u << (mx & 31));
        if (!((old >> (mx & 31)) & 1u)) {
            dedup[e] = 1;
            unsigned key = ((unsigned)mn << 12) | (unsigned)mx;
            unsigned ia = atomicAdd(&elenG[a], 1u);
            if (ia < ECAP) elist[(size_t)a * ECAP + ia] = key;
            unsigned ib = atomicAdd(&elenG[b], 1u);
            if (ib < ECAP) elist[(size_t)b * ECAP + ib] = key;
        }
    }
}

// numpy pairwise f32 sum for n=128 (matches np oracle reduction order)
__global__ void k_pri(const float* __restrict__ f, float* __restrict__ pri) {
    int v = blockIdx.x * 256 + threadIdx.x;
    if (v < V) {
        const float* p = f + v * D;
        float r[8];
#pragma unroll
        for (int j = 0; j < 8; j++) r[j] = __fmul_rn(p[j], p[j]);
        for (int i = 8; i < D; i += 8) {
#pragma unroll
            for (int j = 0; j < 8; j++)
                r[j] = __fadd_rn(r[j], __fmul_rn(p[i + j], p[i + j]));
        }
        float s01 = __fadd_rn(r[0], r[1]);
        float s23 = __fadd_rn(r[2], r[3]);
        float s45 = __fadd_rn(r[4], r[5]);
        float s67 = __fadd_rn(r[6], r[7]);
        pri[v] = __fadd_rn(__fadd_rn(s01, s23), __fadd_rn(s45, s67));
    }
}

__global__ void k_keys(const int* __restrict__ edges, const float* __restrict__ pri,
                       unsigned long long* __restrict__ keys) {
    int s = blockIdx.x * 256 + threadIdx.x;
    if (s < NPAD) {
        unsigned long long rec;
        if (s < E) {
            int a = edges[s], b = edges[E + s];
            float k = __fadd_rn(pri[a], pri[b]);   // epri >= 0 -> bits monotone
            rec = ((unsigned long long)__float_as_uint(k) << 32) | (unsigned)s;
        } else {
            rec = (0xFFFFFFFFull << 32) | (unsigned)s;
        }
        keys[s] = rec;
    }
}

__launch_bounds__(1024)
__global__ void k_sort2(unsigned long long* __restrict__ keys) {
    __shared__ unsigned long long srt[HALF];
    const int tid = threadIdx.x;
    unsigned long long* base = keys + blockIdx.x * HALF;
    for (int s = tid; s < HALF; s += 1024) srt[s] = base[s];
    __syncthreads();
    for (int k = 2; k <= HALF; k <<= 1) {
        for (int j = k >> 1; j >= 1; j >>= 1) {
            for (int i = tid; i < HALF; i += 1024) {
                int ixj = i ^ j;
                if (ixj > i) {
                    unsigned long long x = srt[i], y = srt[ixj];
                    bool up = ((i & k) == 0);
                    if ((x > y) == up) { srt[i] = y; srt[ixj] = x; }
                }
            }
            __syncthreads();
        }
    }
    for (int s = tid; s < HALF; s += 1024) base[s] = srt[s];
}

__launch_bounds__(64)
__global__ void k_mergepath(const unsigned long long* __restrict__ keys,
                            const int* __restrict__ edges, unsigned* __restrict__ pkG) {
    int t = blockIdx.x * 64 + threadIdx.x;
    if (t >= E / 64) return;
    const unsigned long long* A = keys;
    const unsigned long long* B = keys + HALF;
    int d = t * 64;
    int lo = d > HALF ? d - HALF : 0;
    int hi = d < HALF ? d : HALF;
    while (lo < hi) {
        int mid = (lo + hi) >> 1;
        if (A[mid] < B[d - 1 - mid]) lo = mid + 1; else hi = mid;
    }
    int ia = lo, ib = d - lo;
    for (int o = d; o < d + 64; o++) {
        bool takeA = (ib >= HALF) || (ia < HALF && A[ia] < B[ib]);
        unsigned long long r = takeA ? A[ia++] : B[ib++];
        int e = (int)(r & 0xFFFFFFFFull);
        int a = edges[e], b = edges[E + e];
        pkG[o] = ((unsigned)a << 16) | (unsigned)b;
    }
}

__device__ __forceinline__ unsigned canonkey(int a, int b) {
    return a < b ? (((unsigned)a << 12) | (unsigned)b) : (((unsigned)b << 12) | (unsigned)a);
}

__device__ __forceinline__ unsigned hslot(unsigned key) {
    return (key * 2654435761u) >> 17;   // 15-bit slot
}

// insert/increment pair key; slot layout: key<<8 | count8
__device__ __forceinline__ void hinsert(unsigned* H, unsigned key) {
    unsigned s = hslot(key);
    while (true) {
        unsigned v = ((volatile unsigned*)H)[s];
        if ((v >> 8) == key) { atomicAdd(&H[s], 1u); return; }
        if (v == 0u) {
            unsigned old = atomicCAS(&H[s], 0u, (key << 8) | 1u);
            if (old == 0u) return;
            if ((old >> 8) == key) { atomicAdd(&H[s], 1u); return; }
        }
        s = (s + 1) & (HSLOTS - 1);
    }
}

// true iff count(key)==1 (queried pairs always present)
__device__ __forceinline__ bool hcount1(const unsigned* H, unsigned key) {
    unsigned s = hslot(key);
    while (true) {
        unsigned v = ((volatile const unsigned*)H)[s];
        if ((v >> 8) == key) return (v & 255u) == 1u;
        if (v == 0u) return true;       // unreachable for valid queries
        s = (s + 1) & (HSLOTS - 1);
    }
}

__device__ __forceinline__ int findRoot(unsigned short* root, int x) {
    int r = ((volatile unsigned short*)root)[x];
    while (r != x) {                    // path halving
        int rr = ((volatile unsigned short*)root)[r];
        ((volatile unsigned short*)root)[x] = (unsigned short)rr;
        x = r; r = rr;
    }
    return r;
}

// ONE wave: exact sequential greedy via union-find + pair-count hash.
// Predicate O(1): root[a]==a && root[b]==b && paircount==1. No list fixups.
__launch_bounds__(64, 1)
__global__ void k_collapse(const unsigned* __restrict__ pkG, const int* __restrict__ edges,
                           const uint8_t* __restrict__ dedup, const unsigned* __restrict__ elenG,
                           unsigned* elist, unsigned* __restrict__ pairsG,
                           int* __restrict__ mcountG, float* __restrict__ out) {
    __shared__ unsigned H[HSLOTS];        // 128 KB pair-count hash
    __shared__ unsigned short root[V];    // 8 KB union-find
    __shared__ unsigned short elen[V];    // 8 KB cluster incident-edge counts
    const int lane = threadIdx.x;

    for (int s = lane; s < HSLOTS; s += 64) H[s] = 0u;
    for (int v = lane; v < V; v += 64) {
        root[v] = (unsigned short)v;
        unsigned l = elenG[v];
        elen[v] = (unsigned short)(l > ECAP ? ECAP : l);
    }
    __builtin_amdgcn_s_waitcnt(0);
    // hash init: one count per deduped original pair
    for (int e = lane; e < E; e += 64) {
        if (dedup[e]) hinsert(H, canonkey(edges[e], edges[E + e]));
    }
    __builtin_amdgcn_s_waitcnt(0);

    int cnt = V, mcount = 0;
    bool done = false;

    for (int w = 0; w < E && !done; w += 64) {
        unsigned pk = pkG[w + lane];
        const int a = (int)(pk >> 16), b = (int)(pk & 0xFFFFu);
        const unsigned mykey = canonkey(a, b);
        bool flag = (root[a] == a) && (root[b] == b) && hcount1(H, mykey);
        unsigned long long m = __ballot(flag);
        while (m) {
            int i = __ffsll(m) - 1;
            int v0 = __shfl(a, i), v1 = __shfl(b, i);

            if (lane == 0) {
                root[v1] = (unsigned short)v0;
                pairsG[mcount] = ((unsigned)v0 << 16) | (unsigned)v1;
            }
            __builtin_amdgcn_s_waitcnt(0);            // root write visible wave-wide

            // move v1-cluster's incident edges onto v0 (parallel over lanes)
            int lb = elen[v1];
            int wn = elen[v0];
            for (int c0 = 0; c0 < lb; c0 += 64) {
                int j = c0 + lane;
                unsigned ent = 0u; int r = -1;
                if (j < lb) {
                    ent = elist[(size_t)v1 * ECAP + j];
                    int u = (int)(ent >> 12), x = (int)(ent & 4095u);
                    int ru = findRoot(root, u);
                    int rx = findRoot(root, x);
                    r = (ru == v0) ? rx : ru;
                    if (r == v0) r = -1;               // diagonal: edge absorbed
                }
                unsigned long long km = __ballot(r >= 0);
                if (r >= 0) {
                    int pos = wn + (int)__popcll(km & ((1ull << lane) - 1ull));
                    if (pos < ECAP) elist[(size_t)v0 * ECAP + pos] = ent;
                    hinsert(H, canonkey(v0, r));       // multiplicity moves to (v0,r)
                }
                wn += (int)__popcll(km);
            }
            if (lane == 0) elen[v0] = (unsigned short)(wn > ECAP ? ECAP : wn);
            mcount++; cnt--;
            if (cnt == TARGET) { done = true; break; }

            __builtin_amdgcn_s_waitcnt(0);            // drain LDS atomics + global stores

            // O(1) recheck: only v0/v1-incident lanes can change (monotone)
            if (lane == i) flag = false;
            if (flag) {
                if (a == v1 || b == v1) flag = false;                // endpoint died: final
                else if (a == v0 || b == v0) flag = hcount1(H, mykey); // count may have grown
            }
            m = __ballot(flag && lane > i);
        }
    }

    for (int v = lane; v < V; v += 64)
        out[V * D + v] = (root[v] == v) ? 1.0f : 0.0f;
    if (lane == 0) { mcountG[0] = mcount; out[V * D + V] = (float)cnt; }
}

// Replay merge forest: per-vertex (root, weight) then scatter-add w*f[v] into out[root].
__launch_bounds__(256)
__global__ void k_apply(const float* __restrict__ f, const unsigned* __restrict__ pairsG,
                        const int* __restrict__ mcountG, float* __restrict__ out) {
    __shared__ unsigned pl[MAXM];
    __shared__ int rootL[256];
    __shared__ float wL[256];
    const int tid = threadIdx.x;
    const int mc = mcountG[0];
    for (int j = tid; j < mc; j += 256) pl[j] = pairsG[j];
    __syncthreads();
    int cur = blockIdx.x * 256 + tid;
    float w = 1.0f;
    for (int j = 0; j < mc; j++) {
        unsigned p = pl[j];
        int v0 = (int)(p >> 16), v1 = (int)(p & 0xFFFFu);
        if (cur == v1) { cur = v0; w *= 0.5f; }
        else if (cur == v0) w *= 0.5f;
    }
    rootL[tid] = cur;
    wL[tid] = w;
    __syncthreads();
    const int sub = tid >> 7;
    const int d = tid & 127;
    for (int s = 0; s < 256; s += 2) {
        int idx = s + sub;
        int vv = blockIdx.x * 256 + idx;
        atomicAdd(&out[rootL[idx] * D + d], wL[idx] * f[vv * D + d]);
    }
}

extern "C" void kernel_launch(void* const* d_in, const int* in_sizes, int n_in,
                              void* d_out, int out_size, void* d_ws, size_t ws_size,
                              hipStream_t stream) {
    (void)in_sizes; (void)n_in; (void)out_size; (void)ws_size;
    const float* features = (const float*)d_in[0];
    const int* edges = (const int*)d_in[1];
    uint8_t* ws = (uint8_t*)d_ws;
    unsigned* bm = (unsigned*)(ws + WS_BM);
    unsigned* elist = (unsigned*)(ws + WS_ELIST);
    unsigned* elenG = (unsigned*)(ws + WS_ELEN);
    uint8_t* dedup = ws + WS_DEDUP;
    float* pri = (float*)(ws + WS_PRI);
    unsigned long long* keys = (unsigned long long*)(ws + WS_KEYS);
    unsigned* pkG = (unsigned*)(ws + WS_PK);
    unsigned* pairsG = (unsigned*)(ws + WS_PAIRS);
    int* mcountG = (int*)(ws + WS_MCOUNT);
    float* out = (float*)d_out;

    hipMemsetAsync(bm, 0, (size_t)V * (V / 8), stream);
    hipMemsetAsync(elenG, 0, (size_t)V * 4, stream);
    hipMemsetAsync(dedup, 0, (size_t)E, stream);
    hipMemsetAsync(out, 0, (size_t)V * D * sizeof(float), stream);
    k_pri<<<(V + 255) / 256, 256, 0, stream>>>(features, pri);
    k_build<<<(E + 255) / 256, 256, 0, stream>>>(edges, bm, elenG, elist, dedup);
    k_keys<<<(NPAD + 255) / 256, 256, 0, stream>>>(edges, pri, keys);
    k_sort2<<<2, 1024, 0, stream>>>(keys);
    k_mergepath<<<(E / 64 + 63) / 64, 64, 0, stream>>>(keys, edges, pkG);
    k_collapse<<<1, 64, 0, stream>>>(pkG, edges, dedup, elenG, elist, pairsG, mcountG, out);
    k_apply<<<V / 256, 256, 0, stream>>>(features, pairsG, mcountG, out);
}

// Round 12
// 8396.519 us; speedup vs baseline: 1.7441x; 1.7441x over previous
//
#include <hip/hip_runtime.h>
#include <stdint.h>

#define V 4096
#define D 128
#define E 12288
#define NPAD 16384
#define HALF 8192
#define TARGET 2048
#define MAXM (V - TARGET)     // 2048 merges max
#define LDSCAP 16             // LDS entries per vertex
#define GCAP 128              // total entries per vertex (16 LDS + 112 global ovf)

#define WAIT_VM0 0x0F70       // s_waitcnt vmcnt(0)

// ws layout (bytes)
#define WS_BM     0u                               // V*V/8 = 2 MB dedupe bitmap
#define WS_LISTS  (V * (V / 8u))                   // V*GCAP*2 = 1 MB
#define WS_LEN    (WS_LISTS + V * GCAP * 2u)       // V u32
#define WS_PRI    (WS_LEN + V * 4u)                // V f32
#define WS_KEYS   (WS_PRI + V * 4u)                // NPAD u64
#define WS_PK     (WS_KEYS + NPAD * 8u)            // E u32 (sorted packed edges)
#define WS_PAIRS  (WS_PK + E * 4u)                 // MAXM u32
#define WS_MCOUNT (WS_PAIRS + MAXM * 4u)           // int

__global__ void k_build(const int* __restrict__ edges, unsigned* __restrict__ bm,
                        unsigned* __restrict__ lenG, unsigned short* __restrict__ lists) {
    int e = blockIdx.x * 256 + threadIdx.x;
    if (e < E) {
        int a = edges[e], b = edges[E + e];
        int mn = a < b ? a : b, mx = a < b ? b : a;
        unsigned old = atomicOr(&bm[mn * (V / 32) + (mx >> 5)], 1u << (mx & 31));
        if (!((old >> (mx & 31)) & 1u)) {
            unsigned ia = atomicAdd(&lenG[a], 1u);
            if (ia < GCAP) lists[(size_t)a * GCAP + ia] = (unsigned short)((b << 2) | 2);
            unsigned ib = atomicAdd(&lenG[b], 1u);
            if (ib < GCAP) lists[(size_t)b * GCAP + ib] = (unsigned short)((a << 2) | 2);
        }
    }
}

// numpy pairwise f32 sum for n=128 (matches np oracle reduction order)
__global__ void k_pri(const float* __restrict__ f, float* __restrict__ pri) {
    int v = blockIdx.x * 256 + threadIdx.x;
    if (v < V) {
        const float* p = f + v * D;
        float r[8];
#pragma unroll
        for (int j = 0; j < 8; j++) r[j] = __fmul_rn(p[j], p[j]);
        for (int i = 8; i < D; i += 8) {
#pragma unroll
            for (int j = 0; j < 8; j++)
                r[j] = __fadd_rn(r[j], __fmul_rn(p[i + j], p[i + j]));
        }
        float s01 = __fadd_rn(r[0], r[1]);
        float s23 = __fadd_rn(r[2], r[3]);
        float s45 = __fadd_rn(r[4], r[5]);
        float s67 = __fadd_rn(r[6], r[7]);
        pri[v] = __fadd_rn(__fadd_rn(s01, s23), __fadd_rn(s45, s67));
    }
}

__global__ void k_keys(const int* __restrict__ edges, const float* __restrict__ pri,
                       unsigned long long* __restrict__ keys) {
    int s = blockIdx.x * 256 + threadIdx.x;
    if (s < NPAD) {
        unsigned long long rec;
        if (s < E) {
            int a = edges[s], b = edges[E + s];
            float k = __fadd_rn(pri[a], pri[b]);
            rec = ((unsigned long long)__float_as_uint(k) << 32) | (unsigned)s;
        } else {
            rec = (0xFFFFFFFFull << 32) | (unsigned)s;
        }
        keys[s] = rec;
    }
}

__launch_bounds__(1024)
__global__ void k_sort2(unsigned long long* __restrict__ keys) {
    __shared__ unsigned long long srt[HALF];
    const int tid = threadIdx.x;
    unsigned long long* base = keys + blockIdx.x * HALF;
    for (int s = tid; s < HALF; s += 1024) srt[s] = base[s];
    __syncthreads();
    for (int k = 2; k <= HALF; k <<= 1) {
        for (int j = k >> 1; j >= 1; j >>= 1) {
            for (int i = tid; i < HALF; i += 1024) {
                int ixj = i ^ j;
                if (ixj > i) {
                    unsigned long long x = srt[i], y = srt[ixj];
                    bool up = ((i & k) == 0);
                    if ((x > y) == up) { srt[i] = y; srt[ixj] = x; }
                }
            }
            __syncthreads();
        }
    }
    for (int s = tid; s < HALF; s += 1024) base[s] = srt[s];
}

__launch_bounds__(64)
__global__ void k_mergepath(const unsigned long long* __restrict__ keys,
                            const int* __restrict__ edges, unsigned* __restrict__ pkG) {
    int t = blockIdx.x * 64 + threadIdx.x;
    if (t >= E / 64) return;
    const unsigned long long* A = keys;
    const unsigned long long* B = keys + HALF;
    int d = t * 64;
    int lo = d > HALF ? d - HALF : 0;
    int hi = d < HALF ? d : HALF;
    while (lo < hi) {
        int mid = (lo + hi) >> 1;
        if (A[mid] < B[d - 1 - mid]) lo = mid + 1; else hi = mid;
    }
    int ia = lo, ib = d - lo;
    for (int o = d; o < d + 64; o++) {
        bool takeA = (ib >= HALF) || (ia < HALF && A[ia] < B[ib]);
        unsigned long long r = takeA ? A[ia++] : B[ib++];
        int e = (int)(r & 0xFFFFFFFFull);
        int a = edges[e], b = edges[E + e];
        pkG[o] = ((unsigned)a << 16) | (unsigned)b;
    }
}

// scan first n16 (<=16) entries of an LDS row for id; return val or 0
__device__ __forceinline__ int scanRow16(const unsigned short* Lr, int n16, int id) {
    const unsigned* p = (const unsigned*)Lr;
    int found = 0;
#pragma unroll
    for (int i = 0; i < 8; i++) {
        unsigned w = p[i];
        int n0 = 2 * i;
        if (n0 < n16 && (int)((w & 0xFFFFu) >> 2) == id) found = (int)(w & 3u);
        if (n0 + 1 < n16 && (int)(w >> 18) == id) found = (int)((w >> 16) & 3u);
    }
    return found;
}

// scan staged LDS list (4B-aligned) of n entries for id
__device__ __forceinline__ bool inStaged(const unsigned short* s, int n, int id) {
    const unsigned* p = (const unsigned*)s;
    bool f = false;
    int nw = (n + 1) >> 1;
    for (int i = 0; i < nw; i++) {
        unsigned w = p[i];
        if ((int)((w & 0xFFFFu) >> 2) == id) f = true;
        if (2 * i + 1 < n && (int)(w >> 18) == id) f = true;
    }
    return f;
}

// ONE wave: R5 window machine + R7 list algebra + ALL hot state in LDS.
__launch_bounds__(64, 1)
__global__ void k_collapse(const unsigned* __restrict__ pkG, const unsigned* __restrict__ lenG,
                           unsigned short* lists, unsigned* __restrict__ pairsG,
                           int* __restrict__ mcountG, float* __restrict__ out) {
    __shared__ unsigned short L[V * LDSCAP];   // 128 KB adjacency rows (first 16 entries)
    __shared__ uint8_t lenA[V];                // 4 KB: alive<<7 | len
    __shared__ unsigned sc0w[GCAP / 2];        // 256 B staged v0 list
    __shared__ unsigned sc1w[GCAP / 2];        // 256 B staged v1 list
    unsigned short* sc0 = (unsigned short*)sc0w;
    unsigned short* sc1 = (unsigned short*)sc1w;
    const int lane = threadIdx.x;

    // init: stage first 16 entries of every row into LDS; pack alive|len
    {
        const unsigned* g32 = (const unsigned*)lists;
        unsigned* L32 = (unsigned*)L;
        for (int idx = lane; idx < V * (LDSCAP / 2); idx += 64) {
            int row = idx >> 3, word = idx & 7;
            L32[row * 8 + word] = g32[(size_t)row * (GCAP / 2) + word];
        }
        for (int v = lane; v < V; v += 64) {
            unsigned l = lenG[v];
            if (l > 127) l = 127;
            lenA[v] = (uint8_t)(0x80u | l);
        }
    }
    __syncthreads();

    int cnt = V, mcount = 0;
    bool done = false;

    for (int w = 0; w < E && !done; w += 64) {
        unsigned pk = pkG[w + lane];
        const int a = (int)(pk >> 16), b = (int)(pk & 0xFFFFu);
        // initial check (monotone: reject is final)
        bool flag = false;
        {
            uint8_t la8 = lenA[a], lb8 = lenA[b];
            int fv = 0, la = 0;
            if ((la8 & 0x80) && (lb8 & 0x80)) {
                la = la8 & 0x7F;
                fv = scanRow16(L + a * LDSCAP, la < LDSCAP ? la : LDSCAP, b);
            }
            unsigned long long needOvf = __ballot(!fv && la > LDSCAP);
            if (needOvf) {
                __builtin_amdgcn_s_waitcnt(WAIT_VM0);
                if (!fv && la > LDSCAP) {
                    const unsigned short* g = lists + (size_t)a * GCAP;
                    for (int i = LDSCAP; i < la; i++) {
                        unsigned short e = g[i];
                        if ((int)(e >> 2) == b) fv = (int)(e & 3u);
                    }
                }
            }
            flag = (fv == 2);
        }
        unsigned long long m = __ballot(flag);

        while (m && !done) {
            int i = __ffsll(m) - 1;
            int v0 = __shfl(a, i), v1 = __shfl(b, i);
            int l0 = lenA[v0] & 0x7F, lb = lenA[v1] & 0x7F;   // uniform (broadcast read)

            // ---- stage both lists to scratch ----
            if (l0 > LDSCAP || lb > LDSCAP) __builtin_amdgcn_s_waitcnt(WAIT_VM0);
            for (int j = lane; j < l0; j += 64)
                sc0[j] = (j < LDSCAP) ? L[v0 * LDSCAP + j] : lists[(size_t)v0 * GCAP + j];
            for (int j = lane; j < lb; j += 64)
                sc1[j] = (j < LDSCAP) ? L[v1 * LDSCAP + j] : lists[(size_t)v1 * GCAP + j];
            __syncthreads();                                   // S1

            // ---- build merged row v0 (order-preserving compaction) ----
            int wn = 0;
            for (int c = 0; c < l0; c += 64) {
                int j = c + lane;
                unsigned e = (j < l0) ? sc0[j] : 0u;
                int id = (int)(e >> 2);
                bool keep = (j < l0) && (id != v1);
                bool sh = keep && inStaged(sc1, lb, id);
                unsigned long long mk = __ballot(keep);
                int pos = wn + (int)__popcll(mk & ((1ull << lane) - 1ull));
                if (keep && pos < GCAP) {
                    unsigned short ne = sh ? (unsigned short)((id << 2) | 3u) : (unsigned short)e;
                    if (pos < LDSCAP) L[v0 * LDSCAP + pos] = ne;
                    else lists[(size_t)v0 * GCAP + pos] = ne;
                }
                wn += (int)__popcll(mk);
            }
            for (int c = 0; c < lb; c += 64) {
                int j = c + lane;
                unsigned e = (j < lb) ? sc1[j] : 0u;
                int id = (int)(e >> 2);
                bool keep = (j < lb) && (id != v0) && !inStaged(sc0, l0, id);
                unsigned long long mk = __ballot(keep);
                int pos = wn + (int)__popcll(mk & ((1ull << lane) - 1ull));
                if (keep && pos < GCAP) {
                    if (pos < LDSCAP) L[v0 * LDSCAP + pos] = (unsigned short)e;
                    else lists[(size_t)v0 * GCAP + pos] = (unsigned short)e;
                }
                wn += (int)__popcll(mk);
            }
            if (wn > 127) wn = 127;
            if (lane == 0) {
                lenA[v0] = (uint8_t)(0x80u | wn);
                lenA[v1] = 0;                                  // dead
                pairsG[mcount] = ((unsigned)v0 << 16) | (unsigned)v1;
            }

            // ---- fixups: y in N(v1)\{v0}; distinct y per lane -> race-free ----
            {
                bool anyOvfNeed = false;
                int myY[2]; int myLy[2]; unsigned short myE[2];
                int nmy = 0;
                for (int c = 0; c < lb; c += 64) {
                    int j = c + lane;
                    if (j < lb) {
                        unsigned short e = sc1[j];
                        int y = (int)(e >> 2);
                        if (y != v0) {
                            int ly = lenA[y] & 0x7F;
                            myY[nmy] = y; myLy[nmy] = ly; myE[nmy] = e; nmy++;
                            if (ly > LDSCAP) anyOvfNeed = true;
                        }
                    }
                }
                if (__ballot(anyOvfNeed)) __builtin_amdgcn_s_waitcnt(WAIT_VM0);
                for (int q = 0; q < nmy; q++) {
                    int y = myY[q], ly = myLy[q];
                    int p0 = -1, p1 = -1;
                    unsigned tval = (unsigned)(myE[q] & 3u);
                    const unsigned* lp = (const unsigned*)(L + y * LDSCAP);
                    int l16 = ly < LDSCAP ? ly : LDSCAP;
#pragma unroll
                    for (int ii = 0; ii < 8; ii++) {
                        unsigned wv = lp[ii];
                        int n0 = 2 * ii;
                        if (n0 < l16) {
                            int id = (int)((wv & 0xFFFFu) >> 2);
                            if (id == v0) p0 = n0; else if (id == v1) p1 = n0;
                        }
                        if (n0 + 1 < l16) {
                            int id = (int)(wv >> 18);
                            if (id == v0) p0 = n0 + 1; else if (id == v1) p1 = n0 + 1;
                        }
                    }
                    if (ly > LDSCAP) {
                        const unsigned short* g = lists + (size_t)y * GCAP;
                        for (int jj = LDSCAP; jj < ly; jj++) {
                            int id = (int)(g[jj] >> 2);
                            if (id == v0) p0 = jj; else if (id == v1) p1 = jj;
                        }
                    }
                    if (p1 < 0) continue;                      // defensive
                    if (p0 >= 0) {
                        // clamp v0-entry to 3, remove v1-entry (swap last into hole)
                        unsigned short c3 = (unsigned short)((v0 << 2) | 3u);
                        if (p0 < LDSCAP) L[y * LDSCAP + p0] = c3;
                        else lists[(size_t)y * GCAP + p0] = c3;
                        int last = ly - 1;
                        if (p1 != last) {
                            unsigned short le = (last < LDSCAP)
                                ? L[y * LDSCAP + last] : lists[(size_t)y * GCAP + last];
                            if (le == c3 && last == p0) {}     // (can't happen: p0!=last handled)
                            if (p0 == last) le = c3;           // moved entry was the clamped one
                            if (p1 < LDSCAP) L[y * LDSCAP + p1] = le;
                            else lists[(size_t)y * GCAP + p1] = le;
                        }
                        lenA[y] = (uint8_t)(0x80u | (ly - 1));
                    } else {
                        unsigned short ne = (unsigned short)((v0 << 2) | tval);
                        if (p1 < LDSCAP) L[y * LDSCAP + p1] = ne;
                        else lists[(size_t)y * GCAP + p1] = ne;
                    }
                }
            }
            mcount++; cnt--;
            if (cnt == TARGET) { done = true; break; }
            __syncthreads();                                   // S2

            // ---- recheck (monotone; only v0/v1-incident lanes change) ----
            if (lane <= i) flag = false;
            else if (flag) {
                if (a == v1 || b == v1) flag = false;
                else if (a == v0 || b == v0) {
                    int o = (a == v0) ? b : a;
                    int fv = scanRow16(L + v0 * LDSCAP, wn < LDSCAP ? wn : LDSCAP, o);
                    if (!fv && wn > LDSCAP) {
                        __builtin_amdgcn_s_waitcnt(WAIT_VM0);
                        const unsigned short* g = lists + (size_t)v0 * GCAP;
                        for (int jj = LDSCAP; jj < wn; jj++) {
                            unsigned short e = g[jj];
                            if ((int)(e >> 2) == o) fv = (int)(e & 3u);
                        }
                    }
                    flag = (fv == 2);
                }
            }
            m = __ballot(flag);
        }
    }

    __syncthreads();
    for (int v = lane; v < V; v += 64)
        out[V * D + v] = (lenA[v] & 0x80) ? 1.0f : 0.0f;
    if (lane == 0) { mcountG[0] = mcount; out[V * D + V] = (float)cnt; }
}

// Replay merge forest: per-vertex (root, weight) then scatter-add w*f[v] into out[root].
__launch_bounds__(256)
__global__ void k_apply(const float* __restrict__ f, const unsigned* __restrict__ pairsG,
                        const int* __restrict__ mcountG, float* __restrict__ out) {
    __shared__ unsigned pl[MAXM];
    __shared__ int rootL[256];
    __shared__ float wL[256];
    const int tid = threadIdx.x;
    const int mc = mcountG[0];
    for (int j = tid; j < mc; j += 256) pl[j] = pairsG[j];
    __syncthreads();
    int cur = blockIdx.x * 256 + tid;
    float w = 1.0f;
    for (int j = 0; j < mc; j++) {
        unsigned p = pl[j];
        int v0 = (int)(p >> 16), v1 = (int)(p & 0xFFFFu);
        if (cur == v1) { cur = v0; w *= 0.5f; }
        else if (cur == v0) w *= 0.5f;
    }
    rootL[tid] = cur;
    wL[tid] = w;
    __syncthreads();
    const int sub = tid >> 7;
    const int d = tid & 127;
    for (int s = 0; s < 256; s += 2) {
        int idx = s + sub;
        int vv = blockIdx.x * 256 + idx;
        atomicAdd(&out[rootL[idx] * D + d], wL[idx] * f[vv * D + d]);
    }
}

extern "C" void kernel_launch(void* const* d_in, const int* in_sizes, int n_in,
                              void* d_out, int out_size, void* d_ws, size_t ws_size,
                              hipStream_t stream) {
    (void)in_sizes; (void)n_in; (void)out_size; (void)ws_size;
    const float* features = (const float*)d_in[0];
    const int* edges = (const int*)d_in[1];
    uint8_t* ws = (uint8_t*)d_ws;
    unsigned* bm = (unsigned*)(ws + WS_BM);
    unsigned short* lists = (unsigned short*)(ws + WS_LISTS);
    unsigned* lenG = (unsigned*)(ws + WS_LEN);
    float* pri = (float*)(ws + WS_PRI);
    unsigned long long* keys = (unsigned long long*)(ws + WS_KEYS);
    unsigned* pkG = (unsigned*)(ws + WS_PK);
    unsigned* pairsG = (unsigned*)(ws + WS_PAIRS);
    int* mcountG = (int*)(ws + WS_MCOUNT);
    float* out = (float*)d_out;

    hipMemsetAsync(bm, 0, (size_t)V * (V / 8), stream);
    hipMemsetAsync(lenG, 0, (size_t)V * 4, stream);
    hipMemsetAsync(out, 0, (size_t)V * D * sizeof(float), stream);
    k_pri<<<(V + 255) / 256, 256, 0, stream>>>(features, pri);
    k_build<<<(E + 255) / 256, 256, 0, stream>>>(edges, bm, lenG, lists);
    k_keys<<<(NPAD + 255) / 256, 256, 0, stream>>>(edges, pri, keys);
    k_sort2<<<2, 1024, 0, stream>>>(keys);
    k_mergepath<<<(E / 64 + 63) / 64, 64, 0, stream>>>(keys, edges, pkG);
    k_collapse<<<1, 64, 0, stream>>>(pkG, lenG, lists, pairsG, mcountG, out);
    k_apply<<<V / 256, 256, 0, stream>>>(features, pairsG, mcountG, out);
}